// Round 2
// baseline (201.296 us; speedup 1.0000x reference)
//
#include <hip/hip_runtime.h>

#define BLK 256
#define PD 64
#define PI_F 3.14159265358979323846f

// prep -> main channel: 324 T coeffs + 20 LN moments (module-scope, avoids
// any dependence on harness workspace size).
__device__ float g_ws[344];

__device__ __forceinline__ float fast_tanh(float v) {
    float e = __expf(2.0f * v);
    return 1.0f - 2.0f / (e + 1.0f);
}

// Apply 2x2 complex gate to qubit mask M over 16 amps (new_i = sum_j U[i][j] old_j).
template<int M>
__device__ __forceinline__ void gate_apply(float* ar, float* ai,
        float u00r, float u00i, float u01r, float u01i,
        float u10r, float u10i, float u11r, float u11i) {
    #pragma unroll
    for (int i = 0; i < 16; ++i) {
        if (i & M) continue;
        const int j = i | M;
        const float a0r = ar[i], a0i = ai[i], a1r = ar[j], a1i = ai[j];
        ar[i] = u00r*a0r - u00i*a0i + u01r*a1r - u01i*a1i;
        ai[i] = u00r*a0i + u00i*a0r + u01r*a1i + u01i*a1r;
        ar[j] = u10r*a0r - u10i*a0i + u11r*a1r - u11i*a1i;
        ai[j] = u10r*a0i + u10i*a0r + u11r*a1i + u11i*a1r;
    }
}

template<int CM, int TM>
__device__ __forceinline__ void cnotg(float* ar, float* ai) {
    #pragma unroll
    for (int i = 0; i < 16; ++i) {
        if ((i & CM) && !(i & TM)) {
            const int j = i | TM;
            float tp;
            tp = ar[i]; ar[i] = ar[j]; ar[j] = tp;
            tp = ai[i]; ai[i] = ai[j]; ai[j] = tp;
        }
    }
}

// ---- prep: 1 block x 256 threads.
//   g_ws[0..323]   = T[w][t0][t1][t2][t3]: z_w = sum T * prod_u e_u[t_u],
//                    e_u = (1, cos 2phi_u, sin 2phi_u), idx = ((t0*3+t1)*3+t2)*3+t3
//   g_ws[324..343] = LN moments {M(10 sym), v(4), Wbar(4), bbar, bsq}
// Derivation: z_w = (tensor_u v_u)^H H_w (tensor_u v_u), H_w = U^H Z_w U,
//   U = CNOT2*ROT1*CNOT1*ROT0 (x-independent), v_u = (cos phi, -i sin phi).
//   conj(v[i])v[j] per qubit: 00->(1+C)/2, 11->(1-C)/2, 01->-iS/2, 10->+iS/2.
extern "C" __global__ void __launch_bounds__(256)
qbranch_prep(const float* __restrict__ wts, const float* __restrict__ W,
             const float* __restrict__ bias)
{
    __shared__ float gL[64];        // 8 gates x 8 coeffs
    __shared__ float uRe[16][16];   // U columns: uRe[col][row]
    __shared__ float uIm[16][16];
    __shared__ float tL[324];       // 4 x 81 accumulators
    const int t = threadIdx.x;

    // ---- LN moments (wave 0, identical to verified code) ----
    if (t < 64) {
        const float4 wr = reinterpret_cast<const float4*>(W)[t];
        const float bp = bias[t];
        float v[20] = { wr.x*wr.x, wr.x*wr.y, wr.x*wr.z, wr.x*wr.w,
                        wr.y*wr.y, wr.y*wr.z, wr.y*wr.w,
                        wr.z*wr.z, wr.z*wr.w,
                        wr.w*wr.w,
                        wr.x*bp, wr.y*bp, wr.z*bp, wr.w*bp,
                        wr.x, wr.y, wr.z, wr.w,
                        bp, bp*bp };
        #pragma unroll
        for (int o = 32; o > 0; o >>= 1) {
            #pragma unroll
            for (int k = 0; k < 20; ++k) v[k] += __shfl_xor(v[k], o, 64);
        }
        if (t == 0) {
            #pragma unroll
            for (int k = 0; k < 20; ++k) g_ws[324 + k] = v[k] * (1.0f / 64.0f);
        }
    }
    // ---- gate coefficients (identical to verified code) ----
    if (t < 8) {
        const float phi = wts[t * 3 + 0];
        const float th  = wts[t * 3 + 1];
        const float om  = wts[t * 3 + 2];
        float st, ct;  __sincosf(0.5f * th, &st, &ct);
        float sa, ca;  __sincosf(0.5f * (phi + om), &sa, &ca);
        float sb, cb;  __sincosf(0.5f * (phi - om), &sb, &cb);
        float* gg = gL + t * 8;
        gg[0] =  ct * ca;  gg[1] = -ct * sa;   // u00 = ep*ct
        gg[2] = -st * cb;  gg[3] = -st * sb;   // u01 = -conj(em)*st
        gg[4] =  st * cb;  gg[5] = -st * sb;   // u10 = em*st
        gg[6] =  ct * ca;  gg[7] =  ct * sa;   // u11 = conj(ep)*ct
    }
    for (int k = t; k < 324; k += 256) tL[k] = 0.f;
    __syncthreads();

    // ---- build the 16 columns of U by running the verified circuit code on
    //      basis states (ROT0 on e_k = per-qubit column of R0) ----
    if (t < 16) {
        float v0r[4], v0i[4], v1r[4], v1i[4];
        #pragma unroll
        for (int u = 0; u < 4; ++u) {
            const float* g = gL + u * 8;
            const int bsel = (t >> (3 - u)) & 1;
            v0r[u] = bsel ? g[2] : g[0];  v0i[u] = bsel ? g[3] : g[1];
            v1r[u] = bsel ? g[6] : g[4];  v1i[u] = bsel ? g[7] : g[5];
        }
        float Ar[4], Ai[4], Br[4], Bi[4];
        #pragma unroll
        for (int j = 0; j < 4; ++j) {
            const int b0 = j >> 1, b1 = j & 1;
            const float p0r = b0 ? v1r[0] : v0r[0], p0i = b0 ? v1i[0] : v0i[0];
            const float p1r = b1 ? v1r[1] : v0r[1], p1i = b1 ? v1i[1] : v0i[1];
            Ar[j] = p0r*p1r - p0i*p1i;
            Ai[j] = p0r*p1i + p0i*p1r;
            const float p2r = b0 ? v1r[2] : v0r[2], p2i = b0 ? v1i[2] : v0i[2];
            const float p3r = b1 ? v1r[3] : v0r[3], p3i = b1 ? v1i[3] : v0i[3];
            Br[j] = p2r*p3r - p2i*p3i;
            Bi[j] = p2r*p3i + p2i*p3r;
        }
        float ar[16], ai[16];
        #pragma unroll
        for (int i = 0; i < 16; ++i) {
            const int hi = i >> 2, lo = i & 3;
            ar[i] = Ar[hi]*Br[lo] - Ai[hi]*Bi[lo];
            ai[i] = Ar[hi]*Bi[lo] + Ai[hi]*Br[lo];
        }
        cnotg<8, 4>(ar, ai);
        cnotg<4, 2>(ar, ai);
        cnotg<2, 1>(ar, ai);
        cnotg<1, 8>(ar, ai);
        gate_apply<8>(ar, ai, gL[32],gL[33],gL[34],gL[35],gL[36],gL[37],gL[38],gL[39]);
        gate_apply<4>(ar, ai, gL[40],gL[41],gL[42],gL[43],gL[44],gL[45],gL[46],gL[47]);
        gate_apply<2>(ar, ai, gL[48],gL[49],gL[50],gL[51],gL[52],gL[53],gL[54],gL[55]);
        gate_apply<1>(ar, ai, gL[56],gL[57],gL[58],gL[59],gL[60],gL[61],gL[62],gL[63]);
        cnotg<8, 2>(ar, ai);
        cnotg<4, 1>(ar, ai);
        cnotg<2, 8>(ar, ai);
        cnotg<1, 4>(ar, ai);
        #pragma unroll
        for (int m = 0; m < 16; ++m) { uRe[t][m] = ar[m]; uIm[t][m] = ai[m]; }
    }
    __syncthreads();

    // ---- one thread per (i,j): H_w[i,j] then expand into the 81-basis ----
    {
        const int i = t >> 4, j = t & 15;
        float pr[16], pq[16];
        #pragma unroll
        for (int m = 0; m < 16; ++m) {
            const float air = uRe[i][m], aii = uIm[i][m];
            const float ajr = uRe[j][m], aji = uIm[j][m];
            pr[m] = air*ajr + aii*aji;   // Re(conj(U[m,i])*U[m,j])
            pq[m] = air*aji - aii*ajr;   // Im(conj(U[m,i])*U[m,j])
        }
        float hr[4], hq[4];
        #pragma unroll
        for (int w = 0; w < 4; ++w) {
            float sr = 0.f, si = 0.f;
            #pragma unroll
            for (int m = 0; m < 16; ++m) {
                const float sg = ((m >> (3 - w)) & 1) ? -1.f : 1.f;
                sr += sg * pr[m];  si += sg * pq[m];
            }
            hr[w] = sr; hq[w] = si;
        }
        // per-qubit term slots (always 2; unused slot has zero coeff)
        int   tA[4], tB[4];
        float cAr[4], cAi[4], cBr[4], cBi[4];
        #pragma unroll
        for (int u = 0; u < 4; ++u) {
            const int iu = (i >> (3 - u)) & 1, ju = (j >> (3 - u)) & 1;
            if (iu == 0 && ju == 0)      { tA[u]=0; cAr[u]=0.5f; cAi[u]=0.f;  tB[u]=1; cBr[u]= 0.5f; cBi[u]=0.f; }
            else if (iu == 1 && ju == 1) { tA[u]=0; cAr[u]=0.5f; cAi[u]=0.f;  tB[u]=1; cBr[u]=-0.5f; cBi[u]=0.f; }
            else if (iu == 0 && ju == 1) { tA[u]=2; cAr[u]=0.f;  cAi[u]=-0.5f; tB[u]=2; cBr[u]=0.f;  cBi[u]=0.f; }
            else                         { tA[u]=2; cAr[u]=0.f;  cAi[u]= 0.5f; tB[u]=2; cBr[u]=0.f;  cBi[u]=0.f; }
        }
        #pragma unroll
        for (int a0 = 0; a0 < 2; ++a0) {
            const int   x0  = a0 ? tB[0] : tA[0];
            const float p0r = a0 ? cBr[0] : cAr[0], p0i = a0 ? cBi[0] : cAi[0];
            #pragma unroll
            for (int a1 = 0; a1 < 2; ++a1) {
                const int   x1  = a1 ? tB[1] : tA[1];
                const float q1r = a1 ? cBr[1] : cAr[1], q1i = a1 ? cBi[1] : cAi[1];
                const float m1r = p0r*q1r - p0i*q1i, m1i = p0r*q1i + p0i*q1r;
                #pragma unroll
                for (int a2 = 0; a2 < 2; ++a2) {
                    const int   x2  = a2 ? tB[2] : tA[2];
                    const float q2r = a2 ? cBr[2] : cAr[2], q2i = a2 ? cBi[2] : cAi[2];
                    const float m2r = m1r*q2r - m1i*q2i, m2i = m1r*q2i + m1i*q2r;
                    #pragma unroll
                    for (int a3 = 0; a3 < 2; ++a3) {
                        const int   x3  = a3 ? tB[3] : tA[3];
                        const float q3r = a3 ? cBr[3] : cAr[3], q3i = a3 ? cBi[3] : cAi[3];
                        const float m3r = m2r*q3r - m2i*q3i, m3i = m2r*q3i + m2i*q3r;
                        const int idx = ((x0*3 + x1)*3 + x2)*3 + x3;
                        #pragma unroll
                        for (int w = 0; w < 4; ++w) {
                            const float contrib = hr[w]*m3r - hq[w]*m3i;  // Re(H * prod)
                            atomicAdd(&tL[w*81 + idx], contrib);
                        }
                    }
                }
            }
        }
    }
    __syncthreads();
    for (int k = t; k < 324; k += 256) g_ws[k] = tL[k];
}

// ---- main: one thread per batch element; z via 81-coeff multilinear form
//      (coeffs are uniform scalar loads); block-cooperative coalesced epilogue. ----
extern "C" __global__ void __launch_bounds__(BLK)
qbranch_main(const float* __restrict__ x,      // (B,4)
             const float* __restrict__ W,      // (64,4)
             const float* __restrict__ bias,   // (64)
             const float* __restrict__ gamma,  // (64)
             const float* __restrict__ beta,   // (64)
             float* __restrict__ out)          // (B,64) fp32
{
    __shared__ float4 sq4[BLK];   // q0..q3 per row
    __shared__ float2 sms[BLK];   // mu, rstd per row

    const int t = threadIdx.x;
    const int b = blockIdx.x * BLK + t;
    const float4 xv = reinterpret_cast<const float4*>(x)[b];
    const float* cw = g_ws;

    // ---- per-qubit basis (1, cos 2phi, sin 2phi), 2phi = pi * tanh(x) ----
    float C[4], S[4];
    const float xs[4] = {xv.x, xv.y, xv.z, xv.w};
    #pragma unroll
    for (int w = 0; w < 4; ++w)
        __sincosf(PI_F * fast_tanh(xs[w]), &S[w], &C[w]);

    const float e0v[3] = {1.f, C[0], S[0]};
    const float e1v[3] = {1.f, C[1], S[1]};
    const float e2v[3] = {1.f, C[2], S[2]};

    // ---- z_w = sequential tensor contraction of T_w against e3,e2,e1,e0 ----
    float z[4];
    #pragma unroll
    for (int w = 0; w < 4; ++w) {
        const float* T = cw + w * 81;
        float acc0 = 0.f;
        #pragma unroll
        for (int t0 = 0; t0 < 3; ++t0) {
            float acc1 = 0.f;
            #pragma unroll
            for (int t1 = 0; t1 < 3; ++t1) {
                float acc2 = 0.f;
                #pragma unroll
                for (int t2 = 0; t2 < 3; ++t2) {
                    const float* Tp = T + (((t0*3) + t1)*3 + t2)*3;
                    const float r = fmaf(S[3], Tp[2], fmaf(C[3], Tp[1], Tp[0]));
                    acc2 = fmaf(e2v[t2], r, acc2);
                }
                acc1 = fmaf(e1v[t1], acc2, acc1);
            }
            acc0 = fmaf(e0v[t0], acc1, acc0);
        }
        z[w] = acc0;
    }

    // ---- softmax ----
    const float mx = fmaxf(fmaxf(z[0], z[1]), fmaxf(z[2], z[3]));
    const float e0 = __expf(z[0] - mx), e1 = __expf(z[1] - mx);
    const float e2 = __expf(z[2] - mx), e3 = __expf(z[3] - mx);
    const float inv = 1.0f / (e0 + e1 + e2 + e3);
    const float q0 = e0 * inv, q1 = e1 * inv, q2 = e2 * inv, q3 = e3 * inv;

    // ---- LN stats via moments: mu = q.Wbar + bbar; E[h^2] = q^T M q + 2 q.v + bsq ----
    const float* sS = cw + 324;
    const float mu = fmaf(q0, sS[14], fmaf(q1, sS[15], fmaf(q2, sS[16], fmaf(q3, sS[17], sS[18]))));
    const float t0m = sS[0]*q0 + sS[1]*q1 + sS[2]*q2 + sS[3]*q3 + 2.0f*sS[10];
    const float t1m = sS[1]*q0 + sS[4]*q1 + sS[5]*q2 + sS[6]*q3 + 2.0f*sS[11];
    const float t2m = sS[2]*q0 + sS[5]*q1 + sS[7]*q2 + sS[8]*q3 + 2.0f*sS[12];
    const float t3m = sS[3]*q0 + sS[6]*q1 + sS[8]*q2 + sS[9]*q3 + 2.0f*sS[13];
    const float Eh2 = t0m*q0 + t1m*q1 + t2m*q2 + t3m*q3 + sS[19];
    const float rstd = rsqrtf(Eh2 - mu * mu + 1e-5f);

    sq4[t] = make_float4(q0, q1, q2, q3);
    sms[t] = make_float2(mu, rstd);

    // ---- epilogue constants loaded late (short live range, L2-resident) ----
    const int p4 = t & 15;          // this thread's group of 4 output columns
    const float4 w0 = reinterpret_cast<const float4*>(W)[p4 * 4 + 0];
    const float4 w1 = reinterpret_cast<const float4*>(W)[p4 * 4 + 1];
    const float4 w2 = reinterpret_cast<const float4*>(W)[p4 * 4 + 2];
    const float4 w3 = reinterpret_cast<const float4*>(W)[p4 * 4 + 3];
    const float4 bg = reinterpret_cast<const float4*>(bias)[p4];
    const float4 gm = reinterpret_cast<const float4*>(gamma)[p4];
    const float4 bt = reinterpret_cast<const float4*>(beta)[p4];

    __syncthreads();

    // ---- coalesced epilogue: lane (t&15) owns 4 cols, 16 iters cover 256 rows;
    //      wave stores 1 KB contiguous per iter ----
    const int sub = t >> 4;
    const size_t base = (size_t)blockIdx.x * (BLK * PD);
    #pragma unroll 4
    for (int it = 0; it < 16; ++it) {
        const int row = it * 16 + sub;
        const float4 qv = sq4[row];
        const float2 ms = sms[row];
        const float h0 = fmaf(qv.x, w0.x, fmaf(qv.y, w0.y, fmaf(qv.z, w0.z, fmaf(qv.w, w0.w, bg.x))));
        const float h1 = fmaf(qv.x, w1.x, fmaf(qv.y, w1.y, fmaf(qv.z, w1.z, fmaf(qv.w, w1.w, bg.y))));
        const float h2 = fmaf(qv.x, w2.x, fmaf(qv.y, w2.y, fmaf(qv.z, w2.z, fmaf(qv.w, w2.w, bg.z))));
        const float h3 = fmaf(qv.x, w3.x, fmaf(qv.y, w3.y, fmaf(qv.z, w3.z, fmaf(qv.w, w3.w, bg.w))));
        float4 pk;
        pk.x = fmaf((h0 - ms.x), ms.y * gm.x, bt.x);
        pk.y = fmaf((h1 - ms.x), ms.y * gm.y, bt.y);
        pk.z = fmaf((h2 - ms.x), ms.y * gm.z, bt.z);
        pk.w = fmaf((h3 - ms.x), ms.y * gm.w, bt.w);
        *reinterpret_cast<float4*>(&out[base + (size_t)row * PD + p4 * 4]) = pk;
    }
}

extern "C" void kernel_launch(void* const* d_in, const int* in_sizes, int n_in,
                              void* d_out, int out_size, void* d_ws, size_t ws_size,
                              hipStream_t stream) {
    const float* x     = (const float*)d_in[0];
    const float* wts   = (const float*)d_in[1];
    const float* W     = (const float*)d_in[2];
    const float* bias  = (const float*)d_in[3];
    const float* gamma = (const float*)d_in[4];
    const float* beta  = (const float*)d_in[5];
    float* out = (float*)d_out;
    const int B = in_sizes[0] / 4;          // 524288
    hipLaunchKernelGGL(qbranch_prep, dim3(1), dim3(64 * 4), 0, stream, wts, W, bias);
    hipLaunchKernelGGL(qbranch_main, dim3(B / BLK), dim3(BLK), 0, stream,
                       x, W, bias, gamma, beta, out);
}

// Round 3
// 175.197 us; speedup vs baseline: 1.1490x; 1.1490x over previous
//
#include <hip/hip_runtime.h>

#define BLK 256
#define PD 64
#define PI_F 3.14159265358979323846f

__device__ __forceinline__ float fast_tanh(float v) {
    float e = __expf(2.0f * v);
    return 1.0f - 2.0f / (e + 1.0f);
}

// Apply 2x2 complex gate to qubit mask M over 16 amps (new_i = sum_j U[i][j] old_j).
template<int M>
__device__ __forceinline__ void gate_apply(float* ar, float* ai,
        float u00r, float u00i, float u01r, float u01i,
        float u10r, float u10i, float u11r, float u11i) {
    #pragma unroll
    for (int i = 0; i < 16; ++i) {
        if (i & M) continue;
        const int j = i | M;
        const float a0r = ar[i], a0i = ai[i], a1r = ar[j], a1i = ai[j];
        ar[i] = u00r*a0r - u00i*a0i + u01r*a1r - u01i*a1i;
        ai[i] = u00r*a0i + u00i*a0r + u01r*a1i + u01i*a1r;
        ar[j] = u10r*a0r - u10i*a0i + u11r*a1r - u11i*a1i;
        ai[j] = u10r*a0i + u10i*a0r + u11r*a1i + u11i*a1r;
    }
}

template<int CM, int TM>
__device__ __forceinline__ void cnotg(float* ar, float* ai) {
    #pragma unroll
    for (int i = 0; i < 16; ++i) {
        if ((i & CM) && !(i & TM)) {
            const int j = i | TM;
            float tp;
            tp = ar[i]; ar[i] = ar[j]; ar[j] = tp;
            tp = ai[i]; ai[i] = ai[j]; ai[j] = tp;
        }
    }
}

// ---- prep: 1 block x 64 threads. ws[0..63] = 8 gates x 8 coeffs;
//      ws[64..83] = LN moments {M(10 sym), v(4), Wbar(4), bbar, bsq} ----
extern "C" __global__ void __launch_bounds__(64)
qbranch_prep(const float* __restrict__ wts, const float* __restrict__ W,
             const float* __restrict__ bias, float* __restrict__ ws)
{
    const int t = threadIdx.x;
    const float4 wr = reinterpret_cast<const float4*>(W)[t];
    const float bp = bias[t];
    float v[20] = { wr.x*wr.x, wr.x*wr.y, wr.x*wr.z, wr.x*wr.w,
                    wr.y*wr.y, wr.y*wr.z, wr.y*wr.w,
                    wr.z*wr.z, wr.z*wr.w,
                    wr.w*wr.w,
                    wr.x*bp, wr.y*bp, wr.z*bp, wr.w*bp,
                    wr.x, wr.y, wr.z, wr.w,
                    bp, bp*bp };
    #pragma unroll
    for (int o = 32; o > 0; o >>= 1) {
        #pragma unroll
        for (int k = 0; k < 20; ++k) v[k] += __shfl_xor(v[k], o, 64);
    }
    if (t == 0) {
        #pragma unroll
        for (int k = 0; k < 20; ++k) ws[64 + k] = v[k] * (1.0f / 64.0f);
    }
    if (t < 8) {
        const float phi = wts[t * 3 + 0];
        const float th  = wts[t * 3 + 1];
        const float om  = wts[t * 3 + 2];
        float st, ct;  __sincosf(0.5f * th, &st, &ct);
        float sa, ca;  __sincosf(0.5f * (phi + om), &sa, &ca);
        float sb, cb;  __sincosf(0.5f * (phi - om), &sb, &cb);
        float* gg = ws + t * 8;
        gg[0] =  ct * ca;  gg[1] = -ct * sa;   // u00 = ep*ct
        gg[2] = -st * cb;  gg[3] = -st * sb;   // u01 = -conj(em)*st
        gg[4] =  st * cb;  gg[5] = -st * sb;   // u10 = em*st
        gg[6] =  ct * ca;  gg[7] =  ct * sa;   // u11 = conj(ep)*ct
    }
}

// ---- main: one thread per batch element; gates/moments via uniform (scalar)
//      loads from cw; block-cooperative coalesced fp32 epilogue. ----
extern "C" __global__ void __launch_bounds__(BLK)
qbranch_main(const float* __restrict__ x,      // (B,4)
             const float* __restrict__ W,      // (64,4)
             const float* __restrict__ bias,   // (64)
             const float* __restrict__ gamma,  // (64)
             const float* __restrict__ beta,   // (64)
             const float* __restrict__ cw,     // ws: 64 gate coeffs + 20 moments
             float* __restrict__ out)          // (B,64) fp32
{
    __shared__ float4 sq4[BLK];   // q0..q3 per row
    __shared__ float2 sms[BLK];   // mu, rstd per row

    const int t = threadIdx.x;
    const int b = blockIdx.x * BLK + t;
    const float4 xv = reinterpret_cast<const float4*>(x)[b];

    // ---- RX 2-vector per qubit, layer-0 rot folded in (product state) ----
    // RX|0> = (c, -i s); v = U * (c, -i s):
    //   v0 = (c*u00r + s*u01i) + i(c*u00i - s*u01r)
    //   v1 = (c*u10r + s*u11i) + i(c*u10i - s*u11r)
    float v0r[4], v0i[4], v1r[4], v1i[4];
    const float xs[4] = {xv.x, xv.y, xv.z, xv.w};
    #pragma unroll
    for (int w = 0; w < 4; ++w) {
        float s, c;
        __sincosf(0.5f * PI_F * fast_tanh(xs[w]), &s, &c);
        const float g0 = cw[w*8+0], g1 = cw[w*8+1], g2 = cw[w*8+2], g3 = cw[w*8+3];
        const float g4 = cw[w*8+4], g5 = cw[w*8+5], g6 = cw[w*8+6], g7 = cw[w*8+7];
        v0r[w] = fmaf(c, g0,  s * g3);
        v0i[w] = fmaf(c, g1, -s * g2);
        v1r[w] = fmaf(c, g4,  s * g7);
        v1i[w] = fmaf(c, g5, -s * g6);
    }

    // ---- build 16-amp state via pairwise tensor products ----
    // amp index i = (b0 b1 b2 b3), qubit w <-> bit (3-w).  A over (q0,q1), B over (q2,q3).
    float Ar[4], Ai[4], Br[4], Bi[4];
    #pragma unroll
    for (int j = 0; j < 4; ++j) {
        const int b0 = j >> 1, b1 = j & 1;
        const float p0r = b0 ? v1r[0] : v0r[0], p0i = b0 ? v1i[0] : v0i[0];
        const float p1r = b1 ? v1r[1] : v0r[1], p1i = b1 ? v1i[1] : v0i[1];
        Ar[j] = p0r*p1r - p0i*p1i;
        Ai[j] = p0r*p1i + p0i*p1r;
        const float p2r = b0 ? v1r[2] : v0r[2], p2i = b0 ? v1i[2] : v0i[2];
        const float p3r = b1 ? v1r[3] : v0r[3], p3i = b1 ? v1i[3] : v0i[3];
        Br[j] = p2r*p3r - p2i*p3i;
        Bi[j] = p2r*p3i + p2i*p3r;
    }
    float ar[16], ai[16];
    #pragma unroll
    for (int i = 0; i < 16; ++i) {
        const int hi = i >> 2, lo = i & 3;
        ar[i] = Ar[hi]*Br[lo] - Ai[hi]*Bi[lo];
        ai[i] = Ar[hi]*Bi[lo] + Ai[hi]*Br[lo];
    }

    // ---- CNOT ring r=1: (0,1),(1,2),(2,3),(3,0) ----
    cnotg<8, 4>(ar, ai);
    cnotg<4, 2>(ar, ai);
    cnotg<2, 1>(ar, ai);
    cnotg<1, 8>(ar, ai);

    // ---- layer 1 rot gates (entangled state, full apply; coeffs are SGPRs) ----
    gate_apply<8>(ar, ai, cw[32], cw[33], cw[34], cw[35], cw[36], cw[37], cw[38], cw[39]);
    gate_apply<4>(ar, ai, cw[40], cw[41], cw[42], cw[43], cw[44], cw[45], cw[46], cw[47]);
    gate_apply<2>(ar, ai, cw[48], cw[49], cw[50], cw[51], cw[52], cw[53], cw[54], cw[55]);
    gate_apply<1>(ar, ai, cw[56], cw[57], cw[58], cw[59], cw[60], cw[61], cw[62], cw[63]);

    // ---- CNOT ring r=2: (0,2),(1,3),(2,0),(3,1) ----
    cnotg<8, 2>(ar, ai);
    cnotg<4, 1>(ar, ai);
    cnotg<2, 8>(ar, ai);
    cnotg<1, 4>(ar, ai);

    // ---- Z expectations, softmax ----
    float z0 = 0.f, z1 = 0.f, z2 = 0.f, z3 = 0.f;
    #pragma unroll
    for (int i = 0; i < 16; ++i) {
        const float p = ar[i]*ar[i] + ai[i]*ai[i];
        z0 += (i & 8) ? -p : p;
        z1 += (i & 4) ? -p : p;
        z2 += (i & 2) ? -p : p;
        z3 += (i & 1) ? -p : p;
    }
    const float mx = fmaxf(fmaxf(z0, z1), fmaxf(z2, z3));
    const float e0 = __expf(z0 - mx), e1 = __expf(z1 - mx);
    const float e2 = __expf(z2 - mx), e3 = __expf(z3 - mx);
    const float inv = 1.0f / (e0 + e1 + e2 + e3);
    const float q0 = e0 * inv, q1 = e1 * inv, q2 = e2 * inv, q3 = e3 * inv;

    // ---- LN stats via moments: mu = q.Wbar + bbar; E[h^2] = q^T M q + 2 q.v + bsq ----
    const float* sS = cw + 64;
    const float mu = fmaf(q0, sS[14], fmaf(q1, sS[15], fmaf(q2, sS[16], fmaf(q3, sS[17], sS[18]))));
    const float t0 = sS[0]*q0 + sS[1]*q1 + sS[2]*q2 + sS[3]*q3 + 2.0f*sS[10];
    const float t1 = sS[1]*q0 + sS[4]*q1 + sS[5]*q2 + sS[6]*q3 + 2.0f*sS[11];
    const float t2 = sS[2]*q0 + sS[5]*q1 + sS[7]*q2 + sS[8]*q3 + 2.0f*sS[12];
    const float t3 = sS[3]*q0 + sS[6]*q1 + sS[8]*q2 + sS[9]*q3 + 2.0f*sS[13];
    const float Eh2 = t0*q0 + t1*q1 + t2*q2 + t3*q3 + sS[19];
    const float rstd = rsqrtf(Eh2 - mu * mu + 1e-5f);

    sq4[t] = make_float4(q0, q1, q2, q3);
    sms[t] = make_float2(mu, rstd);

    // ---- epilogue constants loaded late (short live range, L2-resident) ----
    const int p4 = t & 15;          // this thread's group of 4 output columns
    const float4 w0 = reinterpret_cast<const float4*>(W)[p4 * 4 + 0];
    const float4 w1 = reinterpret_cast<const float4*>(W)[p4 * 4 + 1];
    const float4 w2 = reinterpret_cast<const float4*>(W)[p4 * 4 + 2];
    const float4 w3 = reinterpret_cast<const float4*>(W)[p4 * 4 + 3];
    const float4 bg = reinterpret_cast<const float4*>(bias)[p4];
    const float4 gm = reinterpret_cast<const float4*>(gamma)[p4];
    const float4 bt = reinterpret_cast<const float4*>(beta)[p4];

    __syncthreads();

    // ---- coalesced epilogue: lane (t&15) owns 4 cols, 16 iters cover 256 rows;
    //      wave stores 1 KB contiguous per iter ----
    const int sub = t >> 4;
    const size_t base = (size_t)blockIdx.x * (BLK * PD);
    #pragma unroll 4
    for (int it = 0; it < 16; ++it) {
        const int row = it * 16 + sub;
        const float4 qv = sq4[row];
        const float2 ms = sms[row];
        const float h0 = fmaf(qv.x, w0.x, fmaf(qv.y, w0.y, fmaf(qv.z, w0.z, fmaf(qv.w, w0.w, bg.x))));
        const float h1 = fmaf(qv.x, w1.x, fmaf(qv.y, w1.y, fmaf(qv.z, w1.z, fmaf(qv.w, w1.w, bg.y))));
        const float h2 = fmaf(qv.x, w2.x, fmaf(qv.y, w2.y, fmaf(qv.z, w2.z, fmaf(qv.w, w2.w, bg.z))));
        const float h3 = fmaf(qv.x, w3.x, fmaf(qv.y, w3.y, fmaf(qv.z, w3.z, fmaf(qv.w, w3.w, bg.w))));
        float4 pk;
        pk.x = fmaf((h0 - ms.x), ms.y * gm.x, bt.x);
        pk.y = fmaf((h1 - ms.x), ms.y * gm.y, bt.y);
        pk.z = fmaf((h2 - ms.x), ms.y * gm.z, bt.z);
        pk.w = fmaf((h3 - ms.x), ms.y * gm.w, bt.w);
        *reinterpret_cast<float4*>(&out[base + (size_t)row * PD + p4 * 4]) = pk;
    }
}

extern "C" void kernel_launch(void* const* d_in, const int* in_sizes, int n_in,
                              void* d_out, int out_size, void* d_ws, size_t ws_size,
                              hipStream_t stream) {
    const float* x     = (const float*)d_in[0];
    const float* wts   = (const float*)d_in[1];
    const float* W     = (const float*)d_in[2];
    const float* bias  = (const float*)d_in[3];
    const float* gamma = (const float*)d_in[4];
    const float* beta  = (const float*)d_in[5];
    float* ws  = (float*)d_ws;
    float* out = (float*)d_out;
    const int B = in_sizes[0] / 4;          // 524288
    hipLaunchKernelGGL(qbranch_prep, dim3(1), dim3(64), 0, stream, wts, W, bias, ws);
    hipLaunchKernelGGL(qbranch_main, dim3(B / BLK), dim3(BLK), 0, stream,
                       x, W, bias, gamma, beta, ws, out);
}